// Round 19
// baseline (3767.698 us; speedup 1.0000x reference)
//
#include <hip/hip_runtime.h>
#include <math.h>

#define SS 2048
#define EE 1024
#define EPSD 1e-8
#define EPSF 1e-8f
#define NTH 256          // 4 waves, 1 per SIMD
#define NW  4
#define NG  32           // cosine groups
#define GS  64           // group size

#define DPP_XOR1 0xB1    // quad_perm [1,0,3,2]
#define DPP_XOR2 0x4E    // quad_perm [2,3,0,1]
#define DPP_HMIR 0x141   // row_half_mirror
#define DPP_MIR  0x140   // row_mirror

using f4 = float __attribute__((ext_vector_type(4)));
using f2 = float __attribute__((ext_vector_type(2)));

// LDS-only barrier (no vmcnt drain; x-traffic is within-thread-only, and
// prefetch DMAs must stay un-drained).
__device__ __forceinline__ void bar_lds() {
  asm volatile("s_waitcnt lgkmcnt(0)" ::: "memory");
  __builtin_amdgcn_s_barrier();
  __builtin_amdgcn_sched_barrier(0);
}

// ---- f32 DPP primitives ----
template <int CTRL>
__device__ __forceinline__ float mov_dpp_f32(float v) {
  union { float f; int i; } a; a.f = v;
  const int n = __builtin_amdgcn_mov_dpp(a.i, CTRL, 0xF, 0xF, true);
  union { int i; float f; } r; r.i = n;
  return r.f;
}

template <int CTRL>
__device__ __forceinline__ float dpp_addf(float v) { return v + mov_dpp_f32<CTRL>(v); }

template <int CTRL>
__device__ __forceinline__ void amax_dppf(float& v, int& ix) {
  const float ov = mov_dpp_f32<CTRL>(v);
  const int oi = __builtin_amdgcn_mov_dpp(ix, CTRL, 0xF, 0xF, true);
  if (ov > v || (ov == v && oi < ix)) { v = ov; ix = oi; }
}

__device__ __forceinline__ void foldmaxf(float& v, int& ix, float ov, int oi) {
  if (ov > v || (ov == v && oi < ix)) { v = ov; ix = oi; }
}

// f32 1/sqrt: v_rsq_f32 + 1 Newton.
__device__ __forceinline__ float rsqrt1f(float x) {
  float y = __builtin_amdgcn_rsqf(x);
  y = y * fmaf(-0.5f * x * y, y, 1.5f);
  return y;
}

// f32 1/x: v_rcp_f32 + 1 Newton.
__device__ __forceinline__ float rcp1f(float x) {
  float y = __builtin_amdgcn_rcpf(x);
  y = y * fmaf(-x, y, 2.0f);
  return y;
}

// f32 tanh for |z| <= ~1.2, rel err ~2e-7.
__device__ __forceinline__ float tanh_f32(float z) {
  const float u = 0.5f * z;
  const float s = u * u;
  float P = fmaf(s, -929569.0f / 638512875.0f, 21844.0f / 6081075.0f);
  P = fmaf(s, P, -1382.0f / 155925.0f);
  P = fmaf(s, P, 62.0f / 2835.0f);
  P = fmaf(s, P, -17.0f / 315.0f);
  P = fmaf(s, P, 2.0f / 15.0f);
  P = fmaf(s, P, -1.0f / 3.0f);
  const float t = fmaf(u * s, P, u);
  const float den = fmaf(t, t, 1.0f);
  return (2.0f * t) * rcp1f(den);
}

__device__ __forceinline__ double wave_sum64(double v) {
#pragma unroll
  for (int off = 32; off > 0; off >>= 1) v += __shfl_down(v, off, 64);
  return v;
}

__global__ void banyan_init(const int* __restrict__ seqs, const float* __restrict__ emb,
                            float* __restrict__ x, double* __restrict__ norms) {
  __shared__ double sh[4];
  const int s = blockIdx.x;
  const int row = seqs[s];
  double acc = 0.0;
  for (int e = threadIdx.x; e < EE; e += 256) {
    const float v = emb[(size_t)row * EE + e];
    x[(size_t)s * EE + e] = v;
    acc += (double)v * (double)v;
  }
  acc = wave_sum64(acc);
  const int lane = threadIdx.x & 63;
  const int w = threadIdx.x >> 6;
  if (lane == 0) sh[w] = acc;
  __syncthreads();
  if (threadIdx.x == 0) norms[s] = sqrt(sh[0] + sh[1] + sh[2] + sh[3]);
}

__global__ void banyan_dots(const float* __restrict__ x, double* __restrict__ num) {
  __shared__ double sh[4];
  const int s = blockIdx.x;
  double acc = 0.0;
  for (int e = threadIdx.x; e < EE; e += 256) {
    acc += (double)x[(size_t)s * EE + e] * (double)x[(size_t)(s + 1) * EE + e];
  }
  acc = wave_sum64(acc);
  const int lane = threadIdx.x & 63;
  const int w = threadIdx.x >> 6;
  if (lane == 0) sh[w] = acc;
  __syncthreads();
  if (threadIdx.x == 0) num[s] = sh[0] + sh[1] + sh[2] + sh[3];
}

// R17 skeleton (best: 2572us) + speculative next-step row prefetch:
// phase-A scan winners' rows (and their list neighbors) are DMA'd to a
// throwaway LDS buffer via global_load_lds — fire-and-forget, never waited
// (bar_lds drains lgkmcnt only) — warming L2 so next step's row loads hit.
__global__ __launch_bounds__(NTH, 1) void banyan_main(
    float* __restrict__ x, const double* __restrict__ norms_in, const double* __restrict__ num_in,
    const float* __restrict__ Wl, const float* __restrict__ Wr, const float* __restrict__ Bb,
    float* __restrict__ out) {
  __shared__ float cosL[SS];
  __shared__ float rcpN[SS];       // 1 / max(norm, eps)
  __shared__ unsigned listL[SS];   // next lo16, prev hi16 (0xFFFF = -1)
  __shared__ int next2L[SS];       // next[next[s]] (-1 = none)
  __shared__ __align__(8) f2 gRec[NG];  // {max, bitcast(idx)} per group
  __shared__ float r3v[3][16];     // [sum][row-slot: w*4 + row]
  __shared__ float pfL[2][18][64]; // prefetch landing zone (garbage, parity-rotated)

  const int t = threadIdx.x;
  const int lane = t & 63;
  const int w = t >> 6;
  const int m16 = lane & 15;
  const float NEGINF = -__builtin_inff();

  for (int s = t; s < SS; s += NTH) {
    rcpN[s] = (float)(1.0 / fmax(norms_in[s], EPSD));
    const int nx = (s + 1 < SS) ? (s + 1) : -1;
    const int pv = s - 1;
    listL[s] = ((unsigned)nx & 0xFFFFu) | (((unsigned)pv & 0xFFFFu) << 16);
    next2L[s] = (s + 2 < SS) ? (s + 2) : -1;
  }
  __syncthreads();
  for (int s = t; s < SS; s += NTH) {
    cosL[s] = (s < SS - 1)
                  ? (float)((num_in[s] * (double)rcpN[s]) * (double)rcpN[s + 1])
                  : NEGINF;
  }
  __syncthreads();
  for (int m = 0; m < NG / NW; ++m) {
    const int g = w * (NG / NW) + m;
    float v = cosL[g * GS + lane];
    int ix = g * GS + lane;
#pragma unroll
    for (int off = 32; off > 0; off >>= 1) {
      const float ov = __shfl_down(v, off, 64);
      const int oi = __shfl_down(ix, off, 64);
      if (ov > v || (ov == v && oi < ix)) { v = ov; ix = oi; }
    }
    if (lane == 0) { f2 r; r.x = v; r.y = __int_as_float(ix); gRec[g] = r; }
  }
  __syncthreads();

  // Thread t owns elements {4t..4t+3}.
  const int e0 = 4 * t;
  const f4 wl = *(const f4*)&Wl[e0];
  const f4 wr = *(const f4*)&Wr[e0];
  const f4 bv = *(const f4*)&Bb[e0];
  int head = 0;

  for (int step = 0; step < SS - 1; ++step) {
    const int par = step & 1;
    // ---- phase 1: argmax over 32 packed group records ----
    const f2 rA = gRec[m16];
    const f2 rB = gRec[m16 + 16];
    float v = rA.x;
    int ix = __float_as_int(rA.y);
    foldmaxf(v, ix, rB.x, __float_as_int(rB.y));
    amax_dppf<DPP_XOR1>(v, ix);
    amax_dppf<DPP_XOR2>(v, ix);
    amax_dppf<DPP_HMIR>(v, ix);
    amax_dppf<DPP_MIR>(v, ix);
    const int i = __builtin_amdgcn_readfirstlane(ix);
    // issue i-row load immediately (don't wait for the list round-trip)
    const f4 xi = *(const f4*)&x[(size_t)i * EE + e0];
    const unsigned pki = listL[i];   // broadcast LDS reads
    const int nj_raw = next2L[i];
    const int j = __builtin_amdgcn_readfirstlane((int)(short)(pki & 0xFFFFu));
    const int p = __builtin_amdgcn_readfirstlane((int)(short)(pki >> 16));
    const int nj = __builtin_amdgcn_readfirstlane(nj_raw);
    if (p < 0) head = j;
    const int p2 = (p >= 0) ? p : i;
    const int n2 = (nj >= 0) ? nj : i;

    // ---- phase 2: remaining row loads; scans + prefetch + tanh in window ----
    const f4 xj = *(const f4*)&x[(size_t)j * EE + e0];
    const f4 xp = *(const f4*)&x[(size_t)p2 * EE + e0];
    const f4 xn = *(const f4*)&x[(size_t)n2 * EE + e0];
    const float rcpP = rcpN[p2];
    const float rcpNN = rcpN[n2];
    const int gi_ = i >> 6;
    const int gp_ = (p >= 0) ? (p >> 6) : gi_;
    const int gj_ = j >> 6;
    const int grp = (w == 0) ? gi_ : (w == 1) ? gp_ : gj_;
    const int base = grp * GS + m16;

    // stable-group scan (masked i/p/j) — runs while the row loads fly.
    float stv = NEGINF; int sti = 0;
    int cand = i;             // this wave's prefetch candidate (uniform)
    if (w < 3) {
      float cc0 = cosL[base];
      float cc1 = cosL[base + 16];
      float cc2 = cosL[base + 32];
      float cc3 = cosL[base + 48];
      const int pos0 = base, pos1 = base + 16, pos2 = base + 32, pos3 = base + 48;
      if (pos0 == i || pos0 == p || pos0 == j) cc0 = NEGINF;
      if (pos1 == i || pos1 == p || pos1 == j) cc1 = NEGINF;
      if (pos2 == i || pos2 == p || pos2 == j) cc2 = NEGINF;
      if (pos3 == i || pos3 == p || pos3 == j) cc3 = NEGINF;
      float cv = cc0; int gx = pos0;
      foldmaxf(cv, gx, cc1, pos1);
      foldmaxf(cv, gx, cc2, pos2);
      foldmaxf(cv, gx, cc3, pos3);
      amax_dppf<DPP_XOR1>(cv, gx);
      amax_dppf<DPP_XOR2>(cv, gx);
      amax_dppf<DPP_HMIR>(cv, gx);
      amax_dppf<DPP_MIR>(cv, gx);
      stv = cv; sti = gx;
      cand = __builtin_amdgcn_readfirstlane(gx) & (SS - 1);
    } else {
      // masked S-scan over untouched groups — PREFETCH CANDIDATE ONLY
      const bool mA = (m16 == gi_) | (m16 == gp_) | (m16 == gj_);
      const int gB = m16 + 16;
      const bool mB = (gB == gi_) | (gB == gp_) | (gB == gj_);
      float sv = mA ? NEGINF : rA.x;
      int si = __float_as_int(rA.y);
      foldmaxf(sv, si, mB ? NEGINF : rB.x, __float_as_int(rB.y));
      amax_dppf<DPP_XOR1>(sv, si);
      amax_dppf<DPP_XOR2>(sv, si);
      amax_dppf<DPP_HMIR>(sv, si);
      amax_dppf<DPP_MIR>(sv, si);
      cand = __builtin_amdgcn_readfirstlane(si) & (SS - 1);
    }
    // candidate's list neighbors (stable slots this step)
    const unsigned lkC = listL[cand];
    const int cN_ = (int)(short)(lkC & 0xFFFFu);
    const int cP_ = (int)(short)(lkC >> 16);
    const int cN2_ = next2L[cand];
    const int cNm = (cN_ >= 0) ? cN_ : cand;
    const int cPm = (cP_ >= 0) ? cP_ : cand;
    const int cN2m = (cN2_ >= 0) ? cN2_ : cand;
    // pp row (w3 extra): p's prev — hi16 of listL[p2] is unchanged this merge
    const unsigned lppA = listL[p2];
    const int ppA = (p >= 0) ? (int)(short)(lppA >> 16) : -1;
    const int ppm = (ppA >= 0) ? ppA : i;

    // ---- speculative prefetch: after real loads (counted-vmcnt safe) ----
    __builtin_amdgcn_sched_barrier(0);
    {
      const size_t lb = (size_t)(lane * 16);  // 64B-stride: covers the 4KB row
      __builtin_amdgcn_global_load_lds(
          (const unsigned int*)&x[(size_t)cand * EE + lb],
          (unsigned int*)&pfL[par][w * 4 + 0][0], 4, 0, 0);
      __builtin_amdgcn_global_load_lds(
          (const unsigned int*)&x[(size_t)cNm * EE + lb],
          (unsigned int*)&pfL[par][w * 4 + 1][0], 4, 0, 0);
      __builtin_amdgcn_global_load_lds(
          (const unsigned int*)&x[(size_t)cPm * EE + lb],
          (unsigned int*)&pfL[par][w * 4 + 2][0], 4, 0, 0);
      __builtin_amdgcn_global_load_lds(
          (const unsigned int*)&x[(size_t)cN2m * EE + lb],
          (unsigned int*)&pfL[par][w * 4 + 3][0], 4, 0, 0);
      if (w == 3) {
        __builtin_amdgcn_global_load_lds(
            (const unsigned int*)&x[(size_t)ppm * EE + lb],
            (unsigned int*)&pfL[par][16][0], 4, 0, 0);
      }
    }

    const float q0 = tanh_f32(fmaf(xi.x, wl.x, fmaf(xj.x, wr.x, bv.x)));
    const float q1 = tanh_f32(fmaf(xi.y, wl.y, fmaf(xj.y, wr.y, bv.y)));
    const float q2 = tanh_f32(fmaf(xi.z, wl.z, fmaf(xj.z, wr.z, bv.z)));
    const float q3 = tanh_f32(fmaf(xi.w, wl.w, fmaf(xj.w, wr.w, bv.w)));

    float s0 = fmaf(q0, q0, fmaf(q1, q1, fmaf(q2, q2, q3 * q3)));
    float s1 = fmaf(xp.x, q0, fmaf(xp.y, q1, fmaf(xp.z, q2, xp.w * q3)));
    float s2 = fmaf(q0, xn.x, fmaf(q1, xn.y, fmaf(q2, xn.z, q3 * xn.w)));
    s1 = (p >= 0) ? s1 : 0.0f;
    s2 = (nj >= 0) ? s2 : 0.0f;
    // DPP-only row reduce (16-lane rows); write 16 row partials
    s0 = dpp_addf<DPP_XOR1>(s0); s1 = dpp_addf<DPP_XOR1>(s1); s2 = dpp_addf<DPP_XOR1>(s2);
    s0 = dpp_addf<DPP_XOR2>(s0); s1 = dpp_addf<DPP_XOR2>(s1); s2 = dpp_addf<DPP_XOR2>(s2);
    s0 = dpp_addf<DPP_HMIR>(s0); s1 = dpp_addf<DPP_HMIR>(s1); s2 = dpp_addf<DPP_HMIR>(s2);
    s0 = dpp_addf<DPP_MIR>(s0);  s1 = dpp_addf<DPP_MIR>(s1);  s2 = dpp_addf<DPP_MIR>(s2);
    if (m16 == 0) {                  // lanes 0,16,32,48: row partials
      const int slot = w * 4 + (lane >> 4);
      r3v[0][slot] = s0; r3v[1][slot] = s1; r3v[2][slot] = s2;
    }
    bar_lds();  // B — LDS-only barrier (prefetches stay in flight)

    // ---- phase 3: parent store (under compute), fold, repair, writes ----
    {
      f4 st; st.x = q0; st.y = q1; st.z = q2; st.w = q3;
      *(f4*)&x[(size_t)j * EE + e0] = st;
    }
    float t0 = r3v[0][m16];
    float t1 = r3v[1][m16];
    float t2 = r3v[2][m16];
    t0 = dpp_addf<DPP_XOR1>(t0); t1 = dpp_addf<DPP_XOR1>(t1); t2 = dpp_addf<DPP_XOR1>(t2);
    t0 = dpp_addf<DPP_XOR2>(t0); t1 = dpp_addf<DPP_XOR2>(t1); t2 = dpp_addf<DPP_XOR2>(t2);
    t0 = dpp_addf<DPP_HMIR>(t0); t1 = dpp_addf<DPP_HMIR>(t1); t2 = dpp_addf<DPP_HMIR>(t2);
    t0 = dpp_addf<DPP_MIR>(t0);  t1 = dpp_addf<DPP_MIR>(t1);  t2 = dpp_addf<DPP_MIR>(t2);
    const float invnn = (t0 > EPSF * EPSF) ? rsqrt1f(t0) : 1e8f;
    const float cosP = (p >= 0) ? (t1 * rcpP) * invnn : NEGINF;
    const float cosJnew = (nj >= 0) ? (t2 * rcpNN) * invnn : NEGINF;
    if (w < 3) {
      float cv = stv; int gx = sti;
      if (p >= 0 && gp_ == grp) foldmaxf(cv, gx, cosP, p);
      if (gj_ == grp) foldmaxf(cv, gx, cosJnew, j);
      if (lane == 0) {              // dup groups: same value written twice
        f2 r; r.x = cv; r.y = __int_as_float(gx);
        gRec[grp] = r;
      }
    } else if (lane == 0) {  // wave 3: scalar LDS state updates
      cosL[i] = NEGINF;
      cosL[j] = cosJnew;
      rcpN[j] = invnn;
      listL[j] = ((unsigned)nj & 0xFFFFu) | (((unsigned)p & 0xFFFFu) << 16);
      if (p >= 0) {
        cosL[p] = cosP;
        const unsigned lp = listL[p];
        listL[p] = (lp & 0xFFFF0000u) | ((unsigned)j & 0xFFFFu);
        next2L[p] = nj;
        const int pp = (int)(short)(lp >> 16);
        if (pp >= 0) next2L[pp] = j;
      }
    }
    bar_lds();  // C — LDS-only barrier
  }

  {
    const f4 h = *(const f4*)&x[(size_t)head * EE + e0];
    *(f4*)&out[e0] = h;
  }
}

extern "C" void kernel_launch(void* const* d_in, const int* in_sizes, int n_in,
                              void* d_out, int out_size, void* d_ws, size_t ws_size,
                              hipStream_t stream) {
  const int* seqs = (const int*)d_in[0];
  const float* emb = (const float*)d_in[1];
  const float* Wl = (const float*)d_in[2];
  const float* Wr = (const float*)d_in[3];
  const float* Bb = (const float*)d_in[4];
  float* out = (float*)d_out;

  const size_t xbytesF = (size_t)SS * EE * sizeof(float);
  float* x = (float*)d_ws;
  double* norms = (double*)((char*)d_ws + xbytesF);
  double* num = norms + SS;
  hipLaunchKernelGGL(banyan_init, dim3(SS), dim3(256), 0, stream, seqs, emb, x, norms);
  hipLaunchKernelGGL(banyan_dots, dim3(SS - 1), dim3(256), 0, stream, x, num);
  hipLaunchKernelGGL(banyan_main, dim3(1), dim3(NTH), 0, stream,
                     x, norms, num, Wl, Wr, Bb, out);
}

// Round 20
// 2797.008 us; speedup vs baseline: 1.3470x; 1.3470x over previous
//
#include <hip/hip_runtime.h>
#include <math.h>

#define SS 2048
#define EE 1024
#define EPSD 1e-8
#define EPSF 1e-8f
#define NTH 256          // 4 waves, 1 per SIMD
#define NW  4
#define NG  32           // cosine groups
#define GS  64           // group size

#define DPP_XOR1 0xB1    // quad_perm [1,0,3,2]
#define DPP_XOR2 0x4E    // quad_perm [2,3,0,1]
#define DPP_HMIR 0x141   // row_half_mirror
#define DPP_MIR  0x140   // row_mirror

using f4 = float __attribute__((ext_vector_type(4)));
using f2 = float __attribute__((ext_vector_type(2)));

// LDS-only barrier (no vmcnt drain; x-traffic is within-thread-only).
__device__ __forceinline__ void bar_lds() {
  asm volatile("s_waitcnt lgkmcnt(0)" ::: "memory");
  __builtin_amdgcn_s_barrier();
  __builtin_amdgcn_sched_barrier(0);
}

// ---- f32 DPP primitives ----
template <int CTRL>
__device__ __forceinline__ float mov_dpp_f32(float v) {
  union { float f; int i; } a; a.f = v;
  const int n = __builtin_amdgcn_mov_dpp(a.i, CTRL, 0xF, 0xF, true);
  union { int i; float f; } r; r.i = n;
  return r.f;
}

template <int CTRL>
__device__ __forceinline__ float dpp_addf(float v) { return v + mov_dpp_f32<CTRL>(v); }

template <int CTRL>
__device__ __forceinline__ void amax_dppf(float& v, int& ix) {
  const float ov = mov_dpp_f32<CTRL>(v);
  const int oi = __builtin_amdgcn_mov_dpp(ix, CTRL, 0xF, 0xF, true);
  if (ov > v || (ov == v && oi < ix)) { v = ov; ix = oi; }
}

// argmax carrying the winner's packed links (pk) and next2 (n2)
template <int CTRL>
__device__ __forceinline__ void amax4_dppf(float& v, int& ix, int& pk, int& n2) {
  const float ov = mov_dpp_f32<CTRL>(v);
  const int oi = __builtin_amdgcn_mov_dpp(ix, CTRL, 0xF, 0xF, true);
  const int op = __builtin_amdgcn_mov_dpp(pk, CTRL, 0xF, 0xF, true);
  const int on = __builtin_amdgcn_mov_dpp(n2, CTRL, 0xF, 0xF, true);
  if (ov > v || (ov == v && oi < ix)) { v = ov; ix = oi; pk = op; n2 = on; }
}

__device__ __forceinline__ void foldmaxf(float& v, int& ix, float ov, int oi) {
  if (ov > v || (ov == v && oi < ix)) { v = ov; ix = oi; }
}

__device__ __forceinline__ void foldmax4(float& v, int& ix, int& pk, int& n2,
                                         float ov, int oi, int opk, int on2) {
  if (ov > v || (ov == v && oi < ix)) { v = ov; ix = oi; pk = opk; n2 = on2; }
}

// f32 1/sqrt: v_rsq_f32 + 1 Newton.
__device__ __forceinline__ float rsqrt1f(float x) {
  float y = __builtin_amdgcn_rsqf(x);
  y = y * fmaf(-0.5f * x * y, y, 1.5f);
  return y;
}

// f32 1/x: v_rcp_f32 + 1 Newton.
__device__ __forceinline__ float rcp1f(float x) {
  float y = __builtin_amdgcn_rcpf(x);
  y = y * fmaf(-x, y, 2.0f);
  return y;
}

// f32 tanh for |z| <= ~1.2, rel err ~2e-7.
__device__ __forceinline__ float tanh_f32(float z) {
  const float u = 0.5f * z;
  const float s = u * u;
  float P = fmaf(s, -929569.0f / 638512875.0f, 21844.0f / 6081075.0f);
  P = fmaf(s, P, -1382.0f / 155925.0f);
  P = fmaf(s, P, 62.0f / 2835.0f);
  P = fmaf(s, P, -17.0f / 315.0f);
  P = fmaf(s, P, 2.0f / 15.0f);
  P = fmaf(s, P, -1.0f / 3.0f);
  const float t = fmaf(u * s, P, u);
  const float den = fmaf(t, t, 1.0f);
  return (2.0f * t) * rcp1f(den);
}

__device__ __forceinline__ double wave_sum64(double v) {
#pragma unroll
  for (int off = 32; off > 0; off >>= 1) v += __shfl_down(v, off, 64);
  return v;
}

__global__ void banyan_init(const int* __restrict__ seqs, const float* __restrict__ emb,
                            float* __restrict__ x, double* __restrict__ norms) {
  __shared__ double sh[4];
  const int s = blockIdx.x;
  const int row = seqs[s];
  double acc = 0.0;
  for (int e = threadIdx.x; e < EE; e += 256) {
    const float v = emb[(size_t)row * EE + e];
    x[(size_t)s * EE + e] = v;
    acc += (double)v * (double)v;
  }
  acc = wave_sum64(acc);
  const int lane = threadIdx.x & 63;
  const int w = threadIdx.x >> 6;
  if (lane == 0) sh[w] = acc;
  __syncthreads();
  if (threadIdx.x == 0) norms[s] = sqrt(sh[0] + sh[1] + sh[2] + sh[3]);
}

__global__ void banyan_dots(const float* __restrict__ x, double* __restrict__ num) {
  __shared__ double sh[4];
  const int s = blockIdx.x;
  double acc = 0.0;
  for (int e = threadIdx.x; e < EE; e += 256) {
    acc += (double)x[(size_t)s * EE + e] * (double)x[(size_t)(s + 1) * EE + e];
  }
  acc = wave_sum64(acc);
  const int lane = threadIdx.x & 63;
  const int w = threadIdx.x >> 6;
  if (lane == 0) sh[w] = acc;
  __syncthreads();
  if (threadIdx.x == 0) num[s] = sh[0] + sh[1] + sh[2] + sh[3];
}

// R17 skeleton (best: 2572us) + link-carrying group records:
// gLnkP/gLnkN hold each group winner's listL/next2L, read alongside gRec and
// carried through the DPP argmax — the listL[i]/next2L[i] round-trip is gone
// and ALL FOUR row loads issue right after the argmax.
__global__ __launch_bounds__(NTH, 1) void banyan_main(
    float* __restrict__ x, const double* __restrict__ norms_in, const double* __restrict__ num_in,
    const float* __restrict__ Wl, const float* __restrict__ Wr, const float* __restrict__ Bb,
    float* __restrict__ out) {
  __shared__ float cosL[SS];
  __shared__ float rcpN[SS];       // 1 / max(norm, eps)
  __shared__ unsigned listL[SS];   // next lo16, prev hi16 (0xFFFF = -1)
  __shared__ int next2L[SS];       // next[next[s]] (-1 = none)
  __shared__ __align__(8) f2 gRec[NG];  // {max, bitcast(idx)} per group
  __shared__ int gLnkP[NG];        // winner's listL (packed next/prev)
  __shared__ int gLnkN[NG];        // winner's next2
  __shared__ float r3v[3][16];     // [sum][row-slot: w*4 + row]

  const int t = threadIdx.x;
  const int lane = t & 63;
  const int w = t >> 6;
  const int m16 = lane & 15;
  const float NEGINF = -__builtin_inff();

  for (int s = t; s < SS; s += NTH) {
    rcpN[s] = (float)(1.0 / fmax(norms_in[s], EPSD));
    const int nx = (s + 1 < SS) ? (s + 1) : -1;
    const int pv = s - 1;
    listL[s] = ((unsigned)nx & 0xFFFFu) | (((unsigned)pv & 0xFFFFu) << 16);
    next2L[s] = (s + 2 < SS) ? (s + 2) : -1;
  }
  __syncthreads();
  for (int s = t; s < SS; s += NTH) {
    cosL[s] = (s < SS - 1)
                  ? (float)((num_in[s] * (double)rcpN[s]) * (double)rcpN[s + 1])
                  : NEGINF;
  }
  __syncthreads();
  for (int m = 0; m < NG / NW; ++m) {
    const int g = w * (NG / NW) + m;
    float v = cosL[g * GS + lane];
    int ix = g * GS + lane;
#pragma unroll
    for (int off = 32; off > 0; off >>= 1) {
      const float ov = __shfl_down(v, off, 64);
      const int oi = __shfl_down(ix, off, 64);
      if (ov > v || (ov == v && oi < ix)) { v = ov; ix = oi; }
    }
    if (lane == 0) { f2 r; r.x = v; r.y = __int_as_float(ix); gRec[g] = r; }
  }
  __syncthreads();
  if (t < NG) {  // fill the winners' link records
    const int ixg = __float_as_int(gRec[t].y) & (SS - 1);
    gLnkP[t] = (int)listL[ixg];
    gLnkN[t] = next2L[ixg];
  }
  __syncthreads();

  // Thread t owns elements {4t..4t+3}.
  const int e0 = 4 * t;
  const f4 wl = *(const f4*)&Wl[e0];
  const f4 wr = *(const f4*)&Wr[e0];
  const f4 bv = *(const f4*)&Bb[e0];
  int head = 0;

  for (int step = 0; step < SS - 1; ++step) {
    // ---- phase 1: argmax over 32 records (val, idx, links all carried) ----
    const f2 rA = gRec[m16];
    const f2 rB = gRec[m16 + 16];
    const int pkA = gLnkP[m16];
    const int pkB = gLnkP[m16 + 16];
    const int n2A = gLnkN[m16];
    const int n2B = gLnkN[m16 + 16];
    float v = rA.x;
    int ix = __float_as_int(rA.y);
    int pkc = pkA;
    int n2c_ = n2A;
    foldmax4(v, ix, pkc, n2c_, rB.x, __float_as_int(rB.y), pkB, n2B);
    amax4_dppf<DPP_XOR1>(v, ix, pkc, n2c_);
    amax4_dppf<DPP_XOR2>(v, ix, pkc, n2c_);
    amax4_dppf<DPP_HMIR>(v, ix, pkc, n2c_);
    amax4_dppf<DPP_MIR>(v, ix, pkc, n2c_);
    const int i = __builtin_amdgcn_readfirstlane(ix);
    const unsigned pkU = (unsigned)__builtin_amdgcn_readfirstlane(pkc);
    const int nj = __builtin_amdgcn_readfirstlane(n2c_);
    const int j = (int)(short)(pkU & 0xFFFFu);
    const int p = (int)(short)(pkU >> 16);
    if (p < 0) head = j;
    const int p2 = (p >= 0) ? p : i;
    const int n2 = (nj >= 0) ? nj : i;

    // ---- all four row loads issue immediately ----
    const f4 xi = *(const f4*)&x[(size_t)i * EE + e0];
    const f4 xj = *(const f4*)&x[(size_t)j * EE + e0];
    const f4 xp = *(const f4*)&x[(size_t)p2 * EE + e0];
    const f4 xn = *(const f4*)&x[(size_t)n2 * EE + e0];

    // ---- phase A (under the load window) ----
    const float rcpP = rcpN[p2];
    const float rcpNN = rcpN[n2];
    const unsigned lpp = listL[p2];
    const int pp = (p >= 0) ? (int)(short)(lpp >> 16) : -1;
    const int n2J = next2L[(j >= 0) ? j : i];   // stable this step
    const int gi_ = i >> 6;
    const int gp_ = (p >= 0) ? (p >> 6) : gi_;
    const int gj_ = j >> 6;
    const int grp = (w == 0) ? gi_ : (w == 1) ? gp_ : gj_;
    const int base = grp * GS + m16;

    // stable-group scan (masked i/p/j) + winner link pre-reads
    float stv = NEGINF; int sti = 0;
    unsigned lkW = 0u; int n2W = -1;
    if (w < 3) {
      float cc0 = cosL[base];
      float cc1 = cosL[base + 16];
      float cc2 = cosL[base + 32];
      float cc3 = cosL[base + 48];
      const int pos0 = base, pos1 = base + 16, pos2 = base + 32, pos3 = base + 48;
      if (pos0 == i || pos0 == p || pos0 == j) cc0 = NEGINF;
      if (pos1 == i || pos1 == p || pos1 == j) cc1 = NEGINF;
      if (pos2 == i || pos2 == p || pos2 == j) cc2 = NEGINF;
      if (pos3 == i || pos3 == p || pos3 == j) cc3 = NEGINF;
      float cv = cc0; int gx = pos0;
      foldmaxf(cv, gx, cc1, pos1);
      foldmaxf(cv, gx, cc2, pos2);
      foldmaxf(cv, gx, cc3, pos3);
      amax_dppf<DPP_XOR1>(cv, gx);
      amax_dppf<DPP_XOR2>(cv, gx);
      amax_dppf<DPP_HMIR>(cv, gx);
      amax_dppf<DPP_MIR>(cv, gx);
      stv = cv; sti = gx;
      const int gxm = __builtin_amdgcn_readfirstlane(gx) & (SS - 1);
      lkW = listL[gxm];        // stable: gx not in {p,j} (masked)
      n2W = next2L[gxm];       // stale only if gx==pp (fixed at repair)
    }

    const float q0 = tanh_f32(fmaf(xi.x, wl.x, fmaf(xj.x, wr.x, bv.x)));
    const float q1 = tanh_f32(fmaf(xi.y, wl.y, fmaf(xj.y, wr.y, bv.y)));
    const float q2 = tanh_f32(fmaf(xi.z, wl.z, fmaf(xj.z, wr.z, bv.z)));
    const float q3 = tanh_f32(fmaf(xi.w, wl.w, fmaf(xj.w, wr.w, bv.w)));

    float s0 = fmaf(q0, q0, fmaf(q1, q1, fmaf(q2, q2, q3 * q3)));
    float s1 = fmaf(xp.x, q0, fmaf(xp.y, q1, fmaf(xp.z, q2, xp.w * q3)));
    float s2 = fmaf(q0, xn.x, fmaf(q1, xn.y, fmaf(q2, xn.z, q3 * xn.w)));
    s1 = (p >= 0) ? s1 : 0.0f;
    s2 = (nj >= 0) ? s2 : 0.0f;
    s0 = dpp_addf<DPP_XOR1>(s0); s1 = dpp_addf<DPP_XOR1>(s1); s2 = dpp_addf<DPP_XOR1>(s2);
    s0 = dpp_addf<DPP_XOR2>(s0); s1 = dpp_addf<DPP_XOR2>(s1); s2 = dpp_addf<DPP_XOR2>(s2);
    s0 = dpp_addf<DPP_HMIR>(s0); s1 = dpp_addf<DPP_HMIR>(s1); s2 = dpp_addf<DPP_HMIR>(s2);
    s0 = dpp_addf<DPP_MIR>(s0);  s1 = dpp_addf<DPP_MIR>(s1);  s2 = dpp_addf<DPP_MIR>(s2);
    if (m16 == 0) {
      const int slot = w * 4 + (lane >> 4);
      r3v[0][slot] = s0; r3v[1][slot] = s1; r3v[2][slot] = s2;
    }
    bar_lds();  // B

    // ---- phase 3: parent store, fold, repair (with links), writes ----
    {
      f4 st; st.x = q0; st.y = q1; st.z = q2; st.w = q3;
      *(f4*)&x[(size_t)j * EE + e0] = st;
    }
    float t0 = r3v[0][m16];
    float t1 = r3v[1][m16];
    float t2 = r3v[2][m16];
    t0 = dpp_addf<DPP_XOR1>(t0); t1 = dpp_addf<DPP_XOR1>(t1); t2 = dpp_addf<DPP_XOR1>(t2);
    t0 = dpp_addf<DPP_XOR2>(t0); t1 = dpp_addf<DPP_XOR2>(t1); t2 = dpp_addf<DPP_XOR2>(t2);
    t0 = dpp_addf<DPP_HMIR>(t0); t1 = dpp_addf<DPP_HMIR>(t1); t2 = dpp_addf<DPP_HMIR>(t2);
    t0 = dpp_addf<DPP_MIR>(t0);  t1 = dpp_addf<DPP_MIR>(t1);  t2 = dpp_addf<DPP_MIR>(t2);
    const float invnn = (t0 > EPSF * EPSF) ? rsqrt1f(t0) : 1e8f;
    const float cosP = (p >= 0) ? (t1 * rcpP) * invnn : NEGINF;
    const float cosJnew = (nj >= 0) ? (t2 * rcpNN) * invnn : NEGINF;
    // post-merge link candidates
    const int pk_p = (int)(((unsigned)j & 0xFFFFu) | (((unsigned)pp & 0xFFFFu) << 16));
    const int pk_j = (int)(((unsigned)nj & 0xFFFFu) | (((unsigned)p & 0xFFFFu) << 16));
    if (w < 3) {
      float cv = stv; int gx = sti;
      int pkw = (int)lkW;
      int n2w = (sti == pp) ? j : n2W;   // within-step next2 staleness fix
      if (p >= 0 && gp_ == grp) foldmax4(cv, gx, pkw, n2w, cosP, p, pk_p, nj);
      if (gj_ == grp) foldmax4(cv, gx, pkw, n2w, cosJnew, j, pk_j, n2J);
      if (lane == 0) {                  // dup groups: same value written twice
        f2 r; r.x = cv; r.y = __int_as_float(gx);
        gRec[grp] = r;
        gLnkP[grp] = pkw;
        gLnkN[grp] = n2w;
      }
    } else if (lane == 0) {  // wave 3: scalar LDS state updates + pp patch
      cosL[i] = NEGINF;
      cosL[j] = cosJnew;
      rcpN[j] = invnn;
      listL[j] = ((unsigned)nj & 0xFFFFu) | (((unsigned)p & 0xFFFFu) << 16);
      if (p >= 0) {
        cosL[p] = cosP;
        listL[p] = (lpp & 0xFFFF0000u) | ((unsigned)j & 0xFFFFu);
        next2L[p] = nj;
        if (pp >= 0) next2L[pp] = j;
      }
      // untouched-group record whose idx == pp has stale next2: patch it
      if (pp >= 0) {
        const int gpp = pp >> 6;
        if (gpp != gi_ && gpp != gp_ && gpp != gj_) {   // no concurrent writer
          if (__float_as_int(gRec[gpp].y) == pp) gLnkN[gpp] = j;
        }
      }
    }
    bar_lds();  // C
  }

  {
    const f4 h = *(const f4*)&x[(size_t)head * EE + e0];
    *(f4*)&out[e0] = h;
  }
}

extern "C" void kernel_launch(void* const* d_in, const int* in_sizes, int n_in,
                              void* d_out, int out_size, void* d_ws, size_t ws_size,
                              hipStream_t stream) {
  const int* seqs = (const int*)d_in[0];
  const float* emb = (const float*)d_in[1];
  const float* Wl = (const float*)d_in[2];
  const float* Wr = (const float*)d_in[3];
  const float* Bb = (const float*)d_in[4];
  float* out = (float*)d_out;

  const size_t xbytesF = (size_t)SS * EE * sizeof(float);
  float* x = (float*)d_ws;
  double* norms = (double*)((char*)d_ws + xbytesF);
  double* num = norms + SS;
  hipLaunchKernelGGL(banyan_init, dim3(SS), dim3(256), 0, stream, seqs, emb, x, norms);
  hipLaunchKernelGGL(banyan_dots, dim3(SS - 1), dim3(256), 0, stream, x, num);
  hipLaunchKernelGGL(banyan_main, dim3(1), dim3(NTH), 0, stream,
                     x, norms, num, Wl, Wr, Bb, out);
}

// Round 21
// 2571.286 us; speedup vs baseline: 1.4653x; 1.0878x over previous
//
#include <hip/hip_runtime.h>
#include <math.h>

#define SS 2048
#define EE 1024
#define EPSD 1e-8
#define EPSF 1e-8f
#define NTH 256          // 4 waves, 1 per SIMD
#define NW  4
#define NG  32           // cosine groups
#define GS  64           // group size

#define DPP_XOR1 0xB1    // quad_perm [1,0,3,2]
#define DPP_XOR2 0x4E    // quad_perm [2,3,0,1]
#define DPP_HMIR 0x141   // row_half_mirror
#define DPP_MIR  0x140   // row_mirror

using f4 = float __attribute__((ext_vector_type(4)));
using f2 = float __attribute__((ext_vector_type(2)));

// LDS-only barrier: __syncthreads() would force s_waitcnt vmcnt(0) (draining
// the in-flight parent store). x-traffic is within-thread-only (thread t
// touches columns 4t..4t+3 of every row), so global ordering is handled by
// the wave's own vmcnt logic; barriers only need LDS visibility.
__device__ __forceinline__ void bar_lds() {
  asm volatile("s_waitcnt lgkmcnt(0)" ::: "memory");
  __builtin_amdgcn_s_barrier();
  __builtin_amdgcn_sched_barrier(0);
}

// ---- f32 DPP primitives (single mov_dpp per stage) ----
template <int CTRL>
__device__ __forceinline__ float mov_dpp_f32(float v) {
  union { float f; int i; } a; a.f = v;
  const int n = __builtin_amdgcn_mov_dpp(a.i, CTRL, 0xF, 0xF, true);
  union { int i; float f; } r; r.i = n;
  return r.f;
}

template <int CTRL>
__device__ __forceinline__ float dpp_addf(float v) { return v + mov_dpp_f32<CTRL>(v); }

template <int CTRL>
__device__ __forceinline__ void amax_dppf(float& v, int& ix) {
  const float ov = mov_dpp_f32<CTRL>(v);
  const int oi = __builtin_amdgcn_mov_dpp(ix, CTRL, 0xF, 0xF, true);
  if (ov > v || (ov == v && oi < ix)) { v = ov; ix = oi; }
}

__device__ __forceinline__ void foldmaxf(float& v, int& ix, float ov, int oi) {
  if (ov > v || (ov == v && oi < ix)) { v = ov; ix = oi; }
}

// f32 1/sqrt: v_rsq_f32 + 1 Newton (~1 ulp).
__device__ __forceinline__ float rsqrt1f(float x) {
  float y = __builtin_amdgcn_rsqf(x);
  y = y * fmaf(-0.5f * x * y, y, 1.5f);
  return y;
}

// f32 1/x: v_rcp_f32 + 1 Newton (~1 ulp).
__device__ __forceinline__ float rcp1f(float x) {
  float y = __builtin_amdgcn_rcpf(x);
  y = y * fmaf(-x, y, 2.0f);
  return y;
}

// f32 tanh for |z| <= ~1.2, rel err ~2e-7: odd Taylor at z/2 (7 terms) + doubling.
__device__ __forceinline__ float tanh_f32(float z) {
  const float u = 0.5f * z;
  const float s = u * u;
  float P = fmaf(s, -929569.0f / 638512875.0f, 21844.0f / 6081075.0f);  // c15,c13
  P = fmaf(s, P, -1382.0f / 155925.0f);   // c11
  P = fmaf(s, P, 62.0f / 2835.0f);        // c9
  P = fmaf(s, P, -17.0f / 315.0f);        // c7
  P = fmaf(s, P, 2.0f / 15.0f);           // c5
  P = fmaf(s, P, -1.0f / 3.0f);           // c3
  const float t = fmaf(u * s, P, u);      // tanh(z/2)
  const float den = fmaf(t, t, 1.0f);
  return (2.0f * t) * rcp1f(den);
}

__device__ __forceinline__ double wave_sum64(double v) {
#pragma unroll
  for (int off = 32; off > 0; off >>= 1) v += __shfl_down(v, off, 64);
  return v;
}

__global__ void banyan_init(const int* __restrict__ seqs, const float* __restrict__ emb,
                            float* __restrict__ x, double* __restrict__ norms) {
  __shared__ double sh[4];
  const int s = blockIdx.x;
  const int row = seqs[s];
  double acc = 0.0;
  for (int e = threadIdx.x; e < EE; e += 256) {
    const float v = emb[(size_t)row * EE + e];
    x[(size_t)s * EE + e] = v;
    acc += (double)v * (double)v;
  }
  acc = wave_sum64(acc);
  const int lane = threadIdx.x & 63;
  const int w = threadIdx.x >> 6;
  if (lane == 0) sh[w] = acc;
  __syncthreads();
  if (threadIdx.x == 0) norms[s] = sqrt(sh[0] + sh[1] + sh[2] + sh[3]);
}

__global__ void banyan_dots(const float* __restrict__ x, double* __restrict__ num) {
  __shared__ double sh[4];
  const int s = blockIdx.x;
  double acc = 0.0;
  for (int e = threadIdx.x; e < EE; e += 256) {
    acc += (double)x[(size_t)s * EE + e] * (double)x[(size_t)(s + 1) * EE + e];
  }
  acc = wave_sum64(acc);
  const int lane = threadIdx.x & 63;
  const int w = threadIdx.x >> 6;
  if (lane == 0) sh[w] = acc;
  __syncthreads();
  if (threadIdx.x == 0) num[s] = sh[0] + sh[1] + sh[2] + sh[3];
}

// R17 (best measured: 2572us): f32 state/arithmetic, crossing-free DPP
// reductions, stable-group scan under the load window, packed group records,
// LDS-only barriers, parent store after barrier B.
__global__ __launch_bounds__(NTH, 1) void banyan_main(
    float* __restrict__ x, const double* __restrict__ norms_in, const double* __restrict__ num_in,
    const float* __restrict__ Wl, const float* __restrict__ Wr, const float* __restrict__ Bb,
    float* __restrict__ out) {
  __shared__ float cosL[SS];
  __shared__ float rcpN[SS];       // 1 / max(norm, eps)
  __shared__ unsigned listL[SS];   // next lo16, prev hi16 (0xFFFF = -1)
  __shared__ int next2L[SS];       // next[next[s]] (-1 = none)
  __shared__ __align__(8) f2 gRec[NG];  // {max, bitcast(idx)} per group
  __shared__ float r3v[3][16];     // [sum][row-slot: w*4 + row]

  const int t = threadIdx.x;
  const int lane = t & 63;
  const int w = t >> 6;
  const int m16 = lane & 15;
  const float NEGINF = -__builtin_inff();

  for (int s = t; s < SS; s += NTH) {
    rcpN[s] = (float)(1.0 / fmax(norms_in[s], EPSD));
    const int nx = (s + 1 < SS) ? (s + 1) : -1;
    const int pv = s - 1;
    listL[s] = ((unsigned)nx & 0xFFFFu) | (((unsigned)pv & 0xFFFFu) << 16);
    next2L[s] = (s + 2 < SS) ? (s + 2) : -1;
  }
  __syncthreads();
  for (int s = t; s < SS; s += NTH) {
    cosL[s] = (s < SS - 1)
                  ? (float)((num_in[s] * (double)rcpN[s]) * (double)rcpN[s + 1])
                  : NEGINF;
  }
  __syncthreads();
  for (int m = 0; m < NG / NW; ++m) {
    const int g = w * (NG / NW) + m;
    float v = cosL[g * GS + lane];
    int ix = g * GS + lane;
#pragma unroll
    for (int off = 32; off > 0; off >>= 1) {
      const float ov = __shfl_down(v, off, 64);
      const int oi = __shfl_down(ix, off, 64);
      if (ov > v || (ov == v && oi < ix)) { v = ov; ix = oi; }
    }
    if (lane == 0) { f2 r; r.x = v; r.y = __int_as_float(ix); gRec[g] = r; }
  }
  __syncthreads();

  // Thread t owns elements {4t, 4t+1, 4t+2, 4t+3} (one 16B chunk).
  const int e0 = 4 * t;
  const f4 wl = *(const f4*)&Wl[e0];
  const f4 wr = *(const f4*)&Wr[e0];
  const f4 bv = *(const f4*)&Bb[e0];
  int head = 0;

  for (int step = 0; step < SS - 1; ++step) {
    // ---- phase 1: argmax over 32 packed group records ----
    const f2 rA = gRec[m16];
    const f2 rB = gRec[m16 + 16];
    float v = rA.x;
    int ix = __float_as_int(rA.y);
    foldmaxf(v, ix, rB.x, __float_as_int(rB.y));
    amax_dppf<DPP_XOR1>(v, ix);
    amax_dppf<DPP_XOR2>(v, ix);
    amax_dppf<DPP_HMIR>(v, ix);
    amax_dppf<DPP_MIR>(v, ix);
    const int i = __builtin_amdgcn_readfirstlane(ix);
    // issue i-row load immediately (don't wait for the list round-trip)
    const f4 xi = *(const f4*)&x[(size_t)i * EE + e0];
    const unsigned pki = listL[i];   // broadcast LDS reads
    const int nj_raw = next2L[i];
    const int j = __builtin_amdgcn_readfirstlane((int)(short)(pki & 0xFFFFu));
    const int p = __builtin_amdgcn_readfirstlane((int)(short)(pki >> 16));
    const int nj = __builtin_amdgcn_readfirstlane(nj_raw);
    if (p < 0) head = j;
    const int p2 = (p >= 0) ? p : i;
    const int n2 = (nj >= 0) ? nj : i;

    // ---- phase 2: remaining row loads; stable scan + tanh in the window ----
    const f4 xj = *(const f4*)&x[(size_t)j * EE + e0];
    const f4 xp = *(const f4*)&x[(size_t)p2 * EE + e0];
    const f4 xn = *(const f4*)&x[(size_t)n2 * EE + e0];
    const float rcpP = rcpN[p2];
    const float rcpNN = rcpN[n2];
    const int gi_ = i >> 6;
    const int gp_ = (p >= 0) ? (p >> 6) : gi_;
    const int gj_ = j >> 6;
    const int grp = (w == 0) ? gi_ : (w == 1) ? gp_ : gj_;
    const int base = grp * GS + m16;

    // stable-group scan (masked i/p/j) — runs while the row loads fly.
    float stv = NEGINF; int sti = 0;
    if (w < 3) {
      float cc0 = cosL[base];
      float cc1 = cosL[base + 16];
      float cc2 = cosL[base + 32];
      float cc3 = cosL[base + 48];
      const int pos0 = base, pos1 = base + 16, pos2 = base + 32, pos3 = base + 48;
      if (pos0 == i || pos0 == p || pos0 == j) cc0 = NEGINF;
      if (pos1 == i || pos1 == p || pos1 == j) cc1 = NEGINF;
      if (pos2 == i || pos2 == p || pos2 == j) cc2 = NEGINF;
      if (pos3 == i || pos3 == p || pos3 == j) cc3 = NEGINF;
      float cv = cc0; int gx = pos0;
      foldmaxf(cv, gx, cc1, pos1);
      foldmaxf(cv, gx, cc2, pos2);
      foldmaxf(cv, gx, cc3, pos3);
      amax_dppf<DPP_XOR1>(cv, gx);
      amax_dppf<DPP_XOR2>(cv, gx);
      amax_dppf<DPP_HMIR>(cv, gx);
      amax_dppf<DPP_MIR>(cv, gx);
      stv = cv; sti = gx;
    }

    const float q0 = tanh_f32(fmaf(xi.x, wl.x, fmaf(xj.x, wr.x, bv.x)));
    const float q1 = tanh_f32(fmaf(xi.y, wl.y, fmaf(xj.y, wr.y, bv.y)));
    const float q2 = tanh_f32(fmaf(xi.z, wl.z, fmaf(xj.z, wr.z, bv.z)));
    const float q3 = tanh_f32(fmaf(xi.w, wl.w, fmaf(xj.w, wr.w, bv.w)));

    float s0 = fmaf(q0, q0, fmaf(q1, q1, fmaf(q2, q2, q3 * q3)));
    float s1 = fmaf(xp.x, q0, fmaf(xp.y, q1, fmaf(xp.z, q2, xp.w * q3)));
    float s2 = fmaf(q0, xn.x, fmaf(q1, xn.y, fmaf(q2, xn.z, q3 * xn.w)));
    s1 = (p >= 0) ? s1 : 0.0f;
    s2 = (nj >= 0) ? s2 : 0.0f;
    // DPP-only row reduce (16-lane rows); write 16 row partials
    s0 = dpp_addf<DPP_XOR1>(s0); s1 = dpp_addf<DPP_XOR1>(s1); s2 = dpp_addf<DPP_XOR1>(s2);
    s0 = dpp_addf<DPP_XOR2>(s0); s1 = dpp_addf<DPP_XOR2>(s1); s2 = dpp_addf<DPP_XOR2>(s2);
    s0 = dpp_addf<DPP_HMIR>(s0); s1 = dpp_addf<DPP_HMIR>(s1); s2 = dpp_addf<DPP_HMIR>(s2);
    s0 = dpp_addf<DPP_MIR>(s0);  s1 = dpp_addf<DPP_MIR>(s1);  s2 = dpp_addf<DPP_MIR>(s2);
    if (m16 == 0) {                  // lanes 0,16,32,48: row partials
      const int slot = w * 4 + (lane >> 4);
      r3v[0][slot] = s0; r3v[1][slot] = s1; r3v[2][slot] = s2;
    }
    bar_lds();  // B — LDS-only barrier, no vmcnt drain

    // ---- phase 3: parent store (issues under compute), fold, repair ----
    {
      f4 st; st.x = q0; st.y = q1; st.z = q2; st.w = q3;
      *(f4*)&x[(size_t)j * EE + e0] = st;
    }
    float t0 = r3v[0][m16];
    float t1 = r3v[1][m16];
    float t2 = r3v[2][m16];
    t0 = dpp_addf<DPP_XOR1>(t0); t1 = dpp_addf<DPP_XOR1>(t1); t2 = dpp_addf<DPP_XOR1>(t2);
    t0 = dpp_addf<DPP_XOR2>(t0); t1 = dpp_addf<DPP_XOR2>(t1); t2 = dpp_addf<DPP_XOR2>(t2);
    t0 = dpp_addf<DPP_HMIR>(t0); t1 = dpp_addf<DPP_HMIR>(t1); t2 = dpp_addf<DPP_HMIR>(t2);
    t0 = dpp_addf<DPP_MIR>(t0);  t1 = dpp_addf<DPP_MIR>(t1);  t2 = dpp_addf<DPP_MIR>(t2);
    const float invnn = (t0 > EPSF * EPSF) ? rsqrt1f(t0) : 1e8f;
    const float cosP = (p >= 0) ? (t1 * rcpP) * invnn : NEGINF;
    const float cosJnew = (nj >= 0) ? (t2 * rcpNN) * invnn : NEGINF;
    if (w < 3) {
      float cv = stv; int gx = sti;
      if (p >= 0 && gp_ == grp) foldmaxf(cv, gx, cosP, p);
      if (gj_ == grp) foldmaxf(cv, gx, cosJnew, j);
      if (lane == 0) {              // dup groups: same value written twice
        f2 r; r.x = cv; r.y = __int_as_float(gx);
        gRec[grp] = r;
      }
    } else if (lane == 0) {  // wave 3: scalar LDS state updates
      cosL[i] = NEGINF;
      cosL[j] = cosJnew;
      rcpN[j] = invnn;
      listL[j] = ((unsigned)nj & 0xFFFFu) | (((unsigned)p & 0xFFFFu) << 16);
      if (p >= 0) {
        cosL[p] = cosP;
        const unsigned lp = listL[p];
        listL[p] = (lp & 0xFFFF0000u) | ((unsigned)j & 0xFFFFu);
        next2L[p] = nj;
        const int pp = (int)(short)(lp >> 16);
        if (pp >= 0) next2L[pp] = j;
      }
    }
    bar_lds();  // C — LDS-only barrier
  }

  {
    const f4 h = *(const f4*)&x[(size_t)head * EE + e0];
    *(f4*)&out[e0] = h;
  }
}

extern "C" void kernel_launch(void* const* d_in, const int* in_sizes, int n_in,
                              void* d_out, int out_size, void* d_ws, size_t ws_size,
                              hipStream_t stream) {
  const int* seqs = (const int*)d_in[0];
  const float* emb = (const float*)d_in[1];
  const float* Wl = (const float*)d_in[2];
  const float* Wr = (const float*)d_in[3];
  const float* Bb = (const float*)d_in[4];
  float* out = (float*)d_out;

  const size_t xbytesF = (size_t)SS * EE * sizeof(float);
  float* x = (float*)d_ws;
  double* norms = (double*)((char*)d_ws + xbytesF);
  double* num = norms + SS;
  hipLaunchKernelGGL(banyan_init, dim3(SS), dim3(256), 0, stream, seqs, emb, x, norms);
  hipLaunchKernelGGL(banyan_dots, dim3(SS - 1), dim3(256), 0, stream, x, num);
  hipLaunchKernelGGL(banyan_main, dim3(1), dim3(NTH), 0, stream,
                     x, norms, num, Wl, Wr, Bb, out);
}